// Round 9
// baseline (130.410 us; speedup 1.0000x reference)
//
#include <hip/hip_runtime.h>
#include <stdint.h>

#define NROW 8192
#define DIM  512
#define NOUT 16
#define GAMMA 0.001f
// exp(2*gamma*c) = exp2(c * 2*gamma*log2(e))
#define EXP2S (2.0f * GAMMA * 1.44269504088896340736f)

typedef __bf16 bf16_t;
typedef bf16_t bf16x4_t __attribute__((ext_vector_type(4)));
typedef bf16_t bf16x8_t __attribute__((ext_vector_type(8)));
typedef float  floatx4_t __attribute__((ext_vector_type(4)));
typedef long   longx2_t __attribute__((ext_vector_type(2)));

// async global->LDS, 16 B/lane. LDS dest is wave-uniform base + lane*16.
__device__ __forceinline__ void async_copy16(const void* g, const void* l) {
    __builtin_amdgcn_global_load_lds(
        (__attribute__((address_space(1))) void*)(uintptr_t)g,
        (__attribute__((address_space(3))) void*)(uint32_t)(uintptr_t)l,
        16, 0, 0);
}

// ---------- prep: fp32 -> fp8 e4m3 rows (K-permuted), norms, alpha' ----------
// Per 64-k group, byte layout: unit u(0..3) of 16B = [kstep0 chunk u (8B) |
// kstep1 chunk u (8B)] so one ds_read_b128 yields both 16x16x32 fp8 operands.
__global__ __launch_bounds__(256) void prep_convert(
    const float* __restrict__ X, const float* __restrict__ T,
    const float* __restrict__ alpha,
    uint8_t* __restrict__ Xf, uint8_t* __restrict__ Tf,
    float* __restrict__ xfac, bf16_t* __restrict__ alphaTp)
{
    const int w = threadIdx.x >> 6, lane = threadIdx.x & 63;
    const int row = blockIdx.x * 4 + w;              // 0..16383
    const bool is_test = row < NROW;
    const float* src = is_test ? X : T;
    uint8_t* dst = is_test ? Xf : Tf;
    const int r = is_test ? row : row - NROW;
    // lane owns floats [lane*8, lane*8+8) = one 8-byte fp8 chunk
    const float4* s4 = (const float4*)(src + (size_t)r * DIM);
    const float4 v0 = s4[lane * 2];
    const float4 v1 = s4[lane * 2 + 1];
    float ss = v0.x*v0.x + v0.y*v0.y + v0.z*v0.z + v0.w*v0.w
             + v1.x*v1.x + v1.y*v1.y + v1.z*v1.z + v1.w*v1.w;
    int lo = __builtin_amdgcn_cvt_pk_fp8_f32(v0.x, v0.y, 0, false);
    lo     = __builtin_amdgcn_cvt_pk_fp8_f32(v0.z, v0.w, lo, true);
    int hi = __builtin_amdgcn_cvt_pk_fp8_f32(v1.x, v1.y, 0, false);
    hi     = __builtin_amdgcn_cvt_pk_fp8_f32(v1.z, v1.w, hi, true);
    // chunk m = lane: group g = m>>3, half h = (m>>2)&1, unit u = m&3
    const int off = (lane >> 3) * 64 + (lane & 3) * 16 + ((lane >> 2) & 1) * 8;
    *(int2*)(dst + (size_t)r * DIM + off) = make_int2(lo, hi);
#pragma unroll
    for (int m = 32; m > 0; m >>= 1) ss += __shfl_xor(ss, m, 64);
    const float f = __expf(-GAMMA * ss);             // all lanes hold the sum
    if (is_test) {
        if (lane == 0) xfac[r] = f;
    } else if (lane < 16) {
        // alphaT'[o][j] = exp(-g*||y_j||^2) * alpha[j][o]
        alphaTp[(size_t)lane * NROW + r] = (bf16_t)(alpha[r * 16 + lane] * f);
    }
}

// ---------- main: fp8 GEMM, persistent X in VGPRs, T-only LDS streaming ------
// Each wave's X (B-operand) slice is invariant across the t-loop: 4 n-tiles x
// 8 k-groups x 16B/lane = 128 VGPRs. Load once via the LDS dbuf at start;
// the K-loop then streams ONLY T through LDS (4 frag reads/group, not 8),
// halving the ds_read_b128 wall (the r7 bottleneck) and halving staging DMA.
#define TPT 4        // train tiles per block (16 chunks x 4 tiles = 8192)
#define KLD2 72      // padded row stride (bf16) of per-wave K'' tile

__global__ __launch_bounds__(256, 2) void rbf_main(
    const uint8_t* __restrict__ Xf, const uint8_t* __restrict__ Tf,
    const bf16_t* __restrict__ alphaTp, const float* __restrict__ xfac,
    float* __restrict__ out)
{
    // layout: buf0 [0,8K), buf1 [8K,16K) (T stream / X init); kw 4x9216 unions
    __shared__ __align__(16) unsigned char smem[4 * 64 * KLD2 * 2];   // 36864 B

    const int tid = threadIdx.x;
    const int w = tid >> 6, lane = tid & 63;
    const int wm = w >> 1, wn = w & 1;               // train half / test half
    const int quad = lane >> 4, l15 = lane & 15;

    const int rb = blockIdx.x;                       // 0..63  test block (XCD = rb%8)
    const int chunk = blockIdx.y;                    // 0..15  train chunk
    const int row0 = rb * 128;
    const int cb0 = chunk * (TPT * 128);

    // staging slot: s_row = tid>>2 (0..63, +64 for 2nd issue), unit = tid&3,
    // global unit = (tid&3) ^ ((row>>1)&3)  (XOR swizzle; invariant under +64)
    const int s_row = tid >> 2;
    const int g_off = (((tid & 3) ^ ((s_row >> 1) & 3)) * 16);
    const uint8_t* gX = Xf + (size_t)(row0 + s_row) * DIM + g_off;
    const uint8_t* gT = Tf + (size_t)(cb0 + s_row) * DIM + g_off;
    const unsigned ldsW = (unsigned)(w << 10);       // wave base in each 4KB slab

    // frag-read swizzle: phys unit16 = quad ^ ((l15>>1)&3)  -> 2-way (free)
    const int xs = ((quad ^ ((l15 >> 1) & 3)) * 16);

    // ---- X init: persistent B-frags (test rows), loaded once via LDS dbuf ----
    longx2_t xr[8][4];                               // 8 k-groups x 4 n-tiles
#pragma unroll
    for (int i = 0; i < 2; ++i)
        async_copy16(gX + (size_t)i * 64 * DIM, smem + i * 4096 + ldsW);
#pragma unroll
    for (int g = 0; g < 8; ++g) {
        __syncthreads();             // drains vmcnt: buf[g&1] landed
        if (g < 7) {
            const unsigned bn = ((g + 1) & 1) * 8192u;
#pragma unroll
            for (int i = 0; i < 2; ++i)
                async_copy16(gX + (size_t)i * 64 * DIM + (g + 1) * 64,
                             smem + bn + i * 4096 + ldsW);
        }
        const unsigned char* bufc = smem + (g & 1) * 8192;
#pragma unroll
        for (int i = 0; i < 4; ++i)
            xr[g][i] = *(const longx2_t*)(bufc + (wn * 64 + i * 16 + l15) * 64 + xs);
    }

    const floatx4_t vzero = {0.f, 0.f, 0.f, 0.f};
    floatx4_t oacc[4];
#pragma unroll
    for (int i = 0; i < 4; ++i) oacc[i] = vzero;

    bf16_t* kw = (bf16_t*)smem + w * (64 * KLD2);    // wave-private K'' region

    for (int t = 0; t < TPT; ++t) {
        const int cb = cb0 + t * 128;
        const uint8_t* gTt = gT + (size_t)t * 128 * DIM;

        floatx4_t acc[4][4];
#pragma unroll
        for (int i = 0; i < 4; ++i)
#pragma unroll
            for (int j = 0; j < 4; ++j) acc[i][j] = vzero;

        __syncthreads();             // all waves done with prev kw/bufs before restage
        // prime: T k-group 0 -> buf0
#pragma unroll
        for (int i = 0; i < 2; ++i)
            async_copy16(gTt + (size_t)i * 64 * DIM, smem + i * 4096 + ldsW);

#pragma unroll
        for (int g = 0; g < 8; ++g) {
            __syncthreads();         // drains vmcnt: buf[g&1] landed (covered issue)
            if (g < 7) {             // issue g+1 into the other buffer
                const unsigned bn = ((g + 1) & 1) * 8192u;
                const int kb = (g + 1) * 64;
#pragma unroll
                for (int i = 0; i < 2; ++i)
                    async_copy16(gTt + (size_t)i * 64 * DIM + kb,
                                 smem + bn + i * 4096 + ldsW);
            }
            const unsigned char* bufc = smem + (g & 1) * 8192;
            longx2_t ta[4];
#pragma unroll
            for (int i = 0; i < 4; ++i)
                ta[i] = *(const longx2_t*)(bufc + (wm * 64 + i * 16 + l15) * 64 + xs);
#pragma unroll
            for (int mi = 0; mi < 4; ++mi)
#pragma unroll
                for (int ni = 0; ni < 4; ++ni)
                    acc[mi][ni] = __builtin_amdgcn_mfma_f32_16x16x32_fp8_fp8(
                        ta[mi].x, xr[g][ni].x, acc[mi][ni], 0, 0, 0);
#pragma unroll
            for (int mi = 0; mi < 4; ++mi)
#pragma unroll
                for (int ni = 0; ni < 4; ++ni)
                    acc[mi][ni] = __builtin_amdgcn_mfma_f32_16x16x32_fp8_fp8(
                        ta[mi].y, xr[g][ni].y, acc[mi][ni], 0, 0, 0);
        }

        __syncthreads();   // all frag reads done before kw overwrites bufs
        // K'' = exp(2*gamma*cross), bf16, test-major kw[test][train], 8B stores
        // acc[mi][ni][r] = cross[train = mi*16+quad*4+r][test = ni*16+l15]
#pragma unroll
        for (int ni = 0; ni < 4; ++ni)
#pragma unroll
            for (int mi = 0; mi < 4; ++mi) {
                bf16x4_t pk;
#pragma unroll
                for (int r = 0; r < 4; ++r)
                    pk[r] = (bf16_t)__builtin_amdgcn_exp2f(acc[mi][ni][r] * EXP2S);
                *(bf16x4_t*)(kw + (ni * 16 + l15) * KLD2 + mi * 16 + quad * 4) = pk;
            }
        // no barrier: each wave reads only its own kw region (in-wave lgkmcnt)

        // epilogue: oacc[ni] += K''[test 16(ni) x train 64] @ alpha'[64 x 16]
#pragma unroll
        for (int ks = 0; ks < 2; ++ks) {
            const bf16x8_t bv = *(const bf16x8_t*)(alphaTp + (size_t)l15 * NROW
                                                   + cb + wm * 64 + ks * 32 + quad * 8);
#pragma unroll
            for (int ni = 0; ni < 4; ++ni) {
                const bf16x8_t av = *(const bf16x8_t*)(kw + (ni * 16 + l15) * KLD2
                                                       + ks * 32 + quad * 8);
                oacc[ni] = __builtin_amdgcn_mfma_f32_16x16x32_bf16(av, bv, oacc[ni], 0, 0, 0);
            }
        }
        // next t: leading __syncthreads() protects kw reads vs restaging
    }

    // reduce the two train halves (wm=0,1) through LDS, then atomicAdd to out
    __syncthreads();
    float* stash = (float*)smem;
    if (wm == 1) {
#pragma unroll
        for (int ni = 0; ni < 4; ++ni)
            *(floatx4_t*)(stash + wn * 1024 + ni * 256 + lane * 4) = oacc[ni];
    }
    __syncthreads();
    if (wm == 0) {
#pragma unroll
        for (int ni = 0; ni < 4; ++ni) {
            const floatx4_t o2 = *(const floatx4_t*)(stash + wn * 1024 + ni * 256 + lane * 4);
            const int trow = row0 + wn * 64 + ni * 16 + quad * 4;
            const float4 xf = *(const float4*)(xfac + trow);
            atomicAdd(out + (size_t)(trow + 0) * NOUT + l15, (oacc[ni][0] + o2[0]) * xf.x);
            atomicAdd(out + (size_t)(trow + 1) * NOUT + l15, (oacc[ni][1] + o2[1]) * xf.y);
            atomicAdd(out + (size_t)(trow + 2) * NOUT + l15, (oacc[ni][2] + o2[2]) * xf.z);
            atomicAdd(out + (size_t)(trow + 3) * NOUT + l15, (oacc[ni][3] + o2[3]) * xf.w);
        }
    }
}

extern "C" void kernel_launch(void* const* d_in, const int* in_sizes, int n_in,
                              void* d_out, int out_size, void* d_ws, size_t ws_size,
                              hipStream_t stream) {
    (void)in_sizes; (void)n_in; (void)out_size; (void)ws_size;
    const float* X     = (const float*)d_in[0];
    const float* T     = (const float*)d_in[1];
    const float* alpha = (const float*)d_in[2];

    char* ws = (char*)d_ws;
    uint8_t* Xf     = (uint8_t*)ws;                                  // 4 MB
    uint8_t* Tf     = (uint8_t*)(ws + (8u << 20));                   // 4 MB
    float*   xfac   = (float*)(ws + (16u << 20));                    // 32 KB
    bf16_t*  alphaTp= (bf16_t*)(ws + (16u << 20) + (64u << 10));     // 256 KB
    float*   out    = (float*)d_out;

    hipMemsetAsync(out, 0, (size_t)NROW * NOUT * sizeof(float), stream);
    prep_convert<<<4096, 256, 0, stream>>>(X, T, alpha, Xf, Tf, xfac, alphaTp);
    dim3 grid(64, 16);   // x = rb (XCD affinity for X), y = chunk
    rbf_main<<<grid, 256, 0, stream>>>(Xf, Tf, alphaTp, xfac, out);
}

// Round 10
// 121.278 us; speedup vs baseline: 1.0753x; 1.0753x over previous
//
#include <hip/hip_runtime.h>
#include <stdint.h>

#define NROW 8192
#define DIM  512
#define NOUT 16
#define GAMMA 0.001f
// exp(2*gamma*c) = exp2(c * 2*gamma*log2(e))
#define EXP2S (2.0f * GAMMA * 1.44269504088896340736f)
#define SC1 0x7F7F7F7F   // e8m0 scale bytes = 127 -> 2^0 = 1.0 (unit scale)

typedef __bf16 bf16_t;
typedef bf16_t bf16x4_t __attribute__((ext_vector_type(4)));
typedef bf16_t bf16x8_t __attribute__((ext_vector_type(8)));
typedef float  floatx4_t __attribute__((ext_vector_type(4)));
typedef int    intx4_t  __attribute__((ext_vector_type(4)));
typedef int    intx8_t  __attribute__((ext_vector_type(8)));

// async global->LDS, 16 B/lane. LDS dest is wave-uniform base + lane*16.
__device__ __forceinline__ void async_copy16(const void* g, const void* l) {
    __builtin_amdgcn_global_load_lds(
        (__attribute__((address_space(1))) void*)(uintptr_t)g,
        (__attribute__((address_space(3))) void*)(uint32_t)(uintptr_t)l,
        16, 0, 0);
}

// ---------- prep: fp32 -> fp8 e4m3 rows (row-major), norms, alpha' ----------
__global__ __launch_bounds__(256) void prep_convert(
    const float* __restrict__ X, const float* __restrict__ T,
    const float* __restrict__ alpha,
    uint8_t* __restrict__ Xf, uint8_t* __restrict__ Tf,
    float* __restrict__ xfac, bf16_t* __restrict__ alphaTp)
{
    const int w = threadIdx.x >> 6, lane = threadIdx.x & 63;
    const int row = blockIdx.x * 4 + w;              // 0..16383
    const bool is_test = row < NROW;
    const float* src = is_test ? X : T;
    uint8_t* dst = is_test ? Xf : Tf;
    const int r = is_test ? row : row - NROW;
    // lane owns floats [lane*8, lane*8+8) -> 8 row-major fp8 bytes
    const float4* s4 = (const float4*)(src + (size_t)r * DIM);
    const float4 v0 = s4[lane * 2];
    const float4 v1 = s4[lane * 2 + 1];
    float ss = v0.x*v0.x + v0.y*v0.y + v0.z*v0.z + v0.w*v0.w
             + v1.x*v1.x + v1.y*v1.y + v1.z*v1.z + v1.w*v1.w;
    int lo = __builtin_amdgcn_cvt_pk_fp8_f32(v0.x, v0.y, 0, false);
    lo     = __builtin_amdgcn_cvt_pk_fp8_f32(v0.z, v0.w, lo, true);
    int hi = __builtin_amdgcn_cvt_pk_fp8_f32(v1.x, v1.y, 0, false);
    hi     = __builtin_amdgcn_cvt_pk_fp8_f32(v1.z, v1.w, hi, true);
    *(int2*)(dst + (size_t)r * DIM + lane * 8) = make_int2(lo, hi);
#pragma unroll
    for (int m = 32; m > 0; m >>= 1) ss += __shfl_xor(ss, m, 64);
    const float f = __expf(-GAMMA * ss);             // all lanes hold the sum
    if (is_test) {
        if (lane == 0) xfac[r] = f;
    } else if (lane < 16) {
        // alphaT'[o][j] = exp(-g*||y_j||^2) * alpha[j][o]
        alphaTp[(size_t)lane * NROW + r] = (bf16_t)(alpha[r * 16 + lane] * f);
    }
}

// ---------- main: MX-scaled fp8 MFMA (K=128, 2x rate), dbuf pipeline --------
// r7/r9 both plateau at 57.5us = the non-scaled fp8 MFMA issue wall (~19.4
// SIMD-cyc/instr, ~33us busy, MfmaUtil 50%). mfma_scale_16x16x128 with unit
// e8m0 scales is the same e4m3 math at 2x rate -> MFMA wall ~16.5us.
// K-groups of 128: 4 per tile (fewer barriers); frag = 32B/lane = 2x b128.
#define TPT 4        // train tiles per block (16 chunks x 4 tiles = 8192)
#define KLD2 72      // padded row stride (bf16) of per-wave K'' tile

__global__ __launch_bounds__(256, 2) void rbf_main(
    const uint8_t* __restrict__ Xf, const uint8_t* __restrict__ Tf,
    const bf16_t* __restrict__ alphaTp, const float* __restrict__ xfac,
    float* __restrict__ out)
{
    // dbuf: buf b at b*32768, each = T[128][128] | X[128][128] fp8 (16K+16K).
    // kw (4 waves x 9216 B = 36K) unions into [0,36864) -- safe: kw written
    // only after post-K-loop barrier, read before next t's restaging barriers.
    __shared__ __align__(16) unsigned char smem[65536];

    const int tid = threadIdx.x;
    const int w = tid >> 6, lane = tid & 63;
    const int wm = w >> 1, wn = w & 1;               // train half / test half
    const int quad = lane >> 4, l15 = lane & 15;

    const int rb = blockIdx.x;                       // 0..63  test block (XCD = rb%8)
    const int chunk = blockIdx.y;                    // 0..15  train chunk
    const int row0 = rb * 128;
    const int cb0 = chunk * (TPT * 128);

    // staging: s_row = tid>>3 (0..31, +32/issue), unit = tid&7,
    // global unit = (tid&7) ^ (s_row&7)  (XOR swizzle; s_row&7 invariant +32)
    const int s_row = tid >> 3;
    const int s_ub = (((tid & 7) ^ (s_row & 7)) * 16);
    const uint8_t* gXp = Xf + (size_t)(row0 + s_row) * DIM + s_ub;
    const uint8_t* gTp = Tf + (size_t)(cb0 + s_row) * DIM + s_ub;
    const unsigned ldsW = (unsigned)(w << 10);       // wave base in each 4KB slab

    const int sw = l15 & 7;                          // frag-read row swizzle key

    const floatx4_t vzero = {0.f, 0.f, 0.f, 0.f};
    floatx4_t oacc[4];
#pragma unroll
    for (int i = 0; i < 4; ++i) oacc[i] = vzero;

    bf16_t* kw = (bf16_t*)smem + w * (64 * KLD2);    // wave-private K'' region

    for (int t = 0; t < TPT; ++t) {
        const int cb = cb0 + t * 128;
        const uint8_t* gTt = gTp + (size_t)t * 128 * DIM;

        floatx4_t acc[4][4];
#pragma unroll
        for (int i = 0; i < 4; ++i)
#pragma unroll
            for (int j = 0; j < 4; ++j) acc[i][j] = vzero;

        __syncthreads();             // all waves done with prev kw/bufs
        // prime: k-group 0 (128 k-bytes) -> buf0
#pragma unroll
        for (int i = 0; i < 4; ++i) {
            async_copy16(gTt + (size_t)i * 16384, smem + i * 4096 + ldsW);
            async_copy16(gXp + (size_t)i * 16384, smem + 16384 + i * 4096 + ldsW);
        }

#pragma unroll
        for (int g = 0; g < 4; ++g) {
            __syncthreads();         // drains vmcnt: buf[g&1] landed (covered issue)
            if (g < 3) {             // issue g+1 into the other buffer
                const unsigned bb = ((g + 1) & 1) * 32768u;
                const int kb = (g + 1) * 128;
#pragma unroll
                for (int i = 0; i < 4; ++i) {
                    async_copy16(gTt + (size_t)i * 16384 + kb, smem + bb + i * 4096 + ldsW);
                    async_copy16(gXp + (size_t)i * 16384 + kb, smem + bb + 16384 + i * 4096 + ldsW);
                }
            }
            const unsigned char* bufc = smem + (g & 1) * 32768;
            intx8_t ta[4], xb[4];
#pragma unroll
            for (int i = 0; i < 4; ++i) {
                const int rA = wm * 64 + i * 16 + l15;
                const intx4_t alo = *(const intx4_t*)(bufc + rA * 128 + (((2 * quad) ^ sw) * 16));
                const intx4_t ahi = *(const intx4_t*)(bufc + rA * 128 + (((2 * quad + 1) ^ sw) * 16));
                ta[i] = __builtin_shufflevector(alo, ahi, 0, 1, 2, 3, 4, 5, 6, 7);
                const int rB = wn * 64 + i * 16 + l15;
                const intx4_t blo = *(const intx4_t*)(bufc + 16384 + rB * 128 + (((2 * quad) ^ sw) * 16));
                const intx4_t bhi = *(const intx4_t*)(bufc + 16384 + rB * 128 + (((2 * quad + 1) ^ sw) * 16));
                xb[i] = __builtin_shufflevector(blo, bhi, 0, 1, 2, 3, 4, 5, 6, 7);
            }
#pragma unroll
            for (int mi = 0; mi < 4; ++mi)
#pragma unroll
                for (int ni = 0; ni < 4; ++ni)
                    acc[mi][ni] = __builtin_amdgcn_mfma_scale_f32_16x16x128_f8f6f4(
                        ta[mi], xb[ni], acc[mi][ni], 0, 0, 0, SC1, 0, SC1);
        }

        __syncthreads();   // all frag reads done before kw overwrites bufs
        // K'' = exp(2*gamma*cross), bf16, test-major kw[test][train], 8B stores
        // acc[mi][ni][r] = cross[train = mi*16+quad*4+r][test = ni*16+l15]
#pragma unroll
        for (int ni = 0; ni < 4; ++ni)
#pragma unroll
            for (int mi = 0; mi < 4; ++mi) {
                bf16x4_t pk;
#pragma unroll
                for (int r = 0; r < 4; ++r)
                    pk[r] = (bf16_t)__builtin_amdgcn_exp2f(acc[mi][ni][r] * EXP2S);
                *(bf16x4_t*)(kw + (ni * 16 + l15) * KLD2 + mi * 16 + quad * 4) = pk;
            }
        // no barrier: each wave reads only its own kw region (in-wave lgkmcnt)

        // epilogue: oacc[ni] += K''[test 16(ni) x train 64] @ alpha'[64 x 16]
#pragma unroll
        for (int ks = 0; ks < 2; ++ks) {
            const bf16x8_t bv = *(const bf16x8_t*)(alphaTp + (size_t)l15 * NROW
                                                   + cb + wm * 64 + ks * 32 + quad * 8);
#pragma unroll
            for (int ni = 0; ni < 4; ++ni) {
                const bf16x8_t av = *(const bf16x8_t*)(kw + (ni * 16 + l15) * KLD2
                                                       + ks * 32 + quad * 8);
                oacc[ni] = __builtin_amdgcn_mfma_f32_16x16x32_bf16(av, bv, oacc[ni], 0, 0, 0);
            }
        }
        // next t: leading __syncthreads() protects kw reads vs restaging
    }

    // reduce the two train halves (wm=0,1) through LDS, then atomicAdd to out
    __syncthreads();
    float* stash = (float*)smem;
    if (wm == 1) {
#pragma unroll
        for (int ni = 0; ni < 4; ++ni)
            *(floatx4_t*)(stash + wn * 1024 + ni * 256 + lane * 4) = oacc[ni];
    }
    __syncthreads();
    if (wm == 0) {
#pragma unroll
        for (int ni = 0; ni < 4; ++ni) {
            const floatx4_t o2 = *(const floatx4_t*)(stash + wn * 1024 + ni * 256 + lane * 4);
            const int trow = row0 + wn * 64 + ni * 16 + quad * 4;
            const float4 xf = *(const float4*)(xfac + trow);
            atomicAdd(out + (size_t)(trow + 0) * NOUT + l15, (oacc[ni][0] + o2[0]) * xf.x);
            atomicAdd(out + (size_t)(trow + 1) * NOUT + l15, (oacc[ni][1] + o2[1]) * xf.y);
            atomicAdd(out + (size_t)(trow + 2) * NOUT + l15, (oacc[ni][2] + o2[2]) * xf.z);
            atomicAdd(out + (size_t)(trow + 3) * NOUT + l15, (oacc[ni][3] + o2[3]) * xf.w);
        }
    }
}

extern "C" void kernel_launch(void* const* d_in, const int* in_sizes, int n_in,
                              void* d_out, int out_size, void* d_ws, size_t ws_size,
                              hipStream_t stream) {
    (void)in_sizes; (void)n_in; (void)out_size; (void)ws_size;
    const float* X     = (const float*)d_in[0];
    const float* T     = (const float*)d_in[1];
    const float* alpha = (const float*)d_in[2];

    char* ws = (char*)d_ws;
    uint8_t* Xf     = (uint8_t*)ws;                                  // 4 MB
    uint8_t* Tf     = (uint8_t*)(ws + (8u << 20));                   // 4 MB
    float*   xfac   = (float*)(ws + (16u << 20));                    // 32 KB
    bf16_t*  alphaTp= (bf16_t*)(ws + (16u << 20) + (64u << 10));     // 256 KB
    float*   out    = (float*)d_out;

    hipMemsetAsync(out, 0, (size_t)NROW * NOUT * sizeof(float), stream);
    prep_convert<<<4096, 256, 0, stream>>>(X, T, alpha, Xf, Tf, xfac, alphaTp);
    dim3 grid(64, 16);   // x = rb (XCD affinity for X), y = chunk
    rbf_main<<<grid, 256, 0, stream>>>(Xf, Tf, alphaTp, xfac, out);
}